// Round 13
// baseline (180.259 us; speedup 1.0000x reference)
//
#include <hip/hip_runtime.h>
#include <cstdint>

// CTC batch cost. R10-R13: two-phase — BW-bound repack + compact serial scan.
// R9 evidence: single-wave gather scan floor ~49us == lines(6/row) x avg-lat
// / per-CU miss-queue depth; same floor as R1's LDS variant -> line traffic
// is the invariant cost. Fix: a WIDE repack kernel (TLP, full chip BW) reads
// the 100MB once and emits lane-ordered bf16 compact data; the serial scan
// then streams ~17 lines/group of L3-warm data via the PROVEN inline-asm
// vmcnt FIFO (R9 skeleton). Scan recurrence unchanged (passed R5/R7/R9).
// (R13 = R10 resubmitted after broker timeouts; no logic change.)

constexpr int BB = 256;
constexpr int TT = 1024;
constexpr int CC = 96;
constexpr int LL = 64;
#define EPSF 1e-7f

typedef __attribute__((ext_vector_type(4))) int i32x4;

__device__ __forceinline__ float wf_shr1_f(float v) {
  int r = __builtin_amdgcn_update_dpp(0, __float_as_int(v), 0x138 /*WAVE_SHR1*/, 0xF, 0xF, false);
  return __int_as_float(r);
}

template <int CTRL>
__device__ __forceinline__ float dpp_max(float v) {
  int r = __builtin_amdgcn_update_dpp(__float_as_int(v), __float_as_int(v), CTRL, 0xF, 0xF, false);
  return fmaxf(v, __int_as_float(r));
}

__device__ __forceinline__ unsigned f2bf(float f) {   // f32 -> bf16 (RNE)
  unsigned x = __float_as_uint(f);
  return (x + 0x7fffu + ((x >> 16) & 1u)) >> 16;
}

// ---------------- Phase 1: repack (wide, BW-bound) ----------------
// grid 4096 = B * 16 tiles; block 256 thr. Per tile: 64 t-rows.
// Output: L[b][g][i][u] bf16 (g=t/8, u=t%8, i=lane) as uint4 rows of 16B;
//         Bk[b][t] bf16 blank stream.
__global__ void __launch_bounds__(256)
ctc_repack(const int* __restrict__ y_true, const float* __restrict__ y_pred,
           unsigned* __restrict__ Lout /*uint4-aligned*/, ushort* __restrict__ Bout) {
  __shared__ alignas(16) float tile[64 * CC];   // 24 KB
  __shared__ int labs[64];
  const int blk = blockIdx.x;
  const int b   = blk >> 4;
  const int t0  = (blk & 15) * 64;
  const int tid = threadIdx.x;

  if (tid < 64) labs[tid] = y_true[b * LL + tid];
  const float* src = y_pred + ((size_t)b * TT + t0) * CC;
#pragma unroll
  for (int j = 0; j < 6; ++j)
    reinterpret_cast<float4*>(tile)[j * 256 + tid] =
        reinterpret_cast<const float4*>(src)[j * 256 + tid];
  __syncthreads();

  const int i   = tid & 63;
  const int gp  = tid >> 6;            // 0..3
  const int lab = labs[i];
#pragma unroll
  for (int k = 0; k < 2; ++k) {
    const int gl = gp * 2 + k;         // local group 0..7
    unsigned o0, o1, o2, o3;
    {
      unsigned a, c;
      a = f2bf(tile[(gl * 8 + 0) * CC + lab]); c = f2bf(tile[(gl * 8 + 1) * CC + lab]); o0 = a | (c << 16);
      a = f2bf(tile[(gl * 8 + 2) * CC + lab]); c = f2bf(tile[(gl * 8 + 3) * CC + lab]); o1 = a | (c << 16);
      a = f2bf(tile[(gl * 8 + 4) * CC + lab]); c = f2bf(tile[(gl * 8 + 5) * CC + lab]); o2 = a | (c << 16);
      a = f2bf(tile[(gl * 8 + 6) * CC + lab]); c = f2bf(tile[(gl * 8 + 7) * CC + lab]); o3 = a | (c << 16);
    }
    const int g = b * 128 + (t0 >> 3) + gl;      // global group id
    reinterpret_cast<uint4*>(Lout)[(size_t)g * 64 + i] = make_uint4(o0, o1, o2, o3);
  }
  if (tid < 64) Bout[(size_t)b * TT + t0 + tid] = (ushort)f2bf(tile[tid * CC + (CC - 1)]);
}

// ---------------- Phase 2: serial scan on compact data ----------------
#define GLX4(dst, ptr, OFF)                                            \
  asm volatile("global_load_dwordx4 %0, %1, off offset:" #OFF          \
               : "=&v"(dst) : "v"(ptr))

#define WAITN(N) do {                                                  \
    asm volatile("s_waitcnt vmcnt(" #N ")" ::: "memory");              \
    __builtin_amdgcn_sched_barrier(0);                                 \
  } while (0)

// issue group into slot s: label pack (per-lane) + blank pack (broadcast)
#define ISSUE(s, OFF, BOFF) do {                                       \
    GLX4(Lv[s], ql, OFF);                                              \
    GLX4(Bv[s], qb, BOFF);                                             \
  } while (0)

#define ADV do { ql += 4096; qb += 64; } while (0)

#define STEP8(s) do {                                                  \
    _Pragma("unroll")                                                  \
    for (int u = 0; u < 8; ++u) {                                      \
      const int ld = Lv[s][u >> 1];                                    \
      const int bd = Bv[s][u >> 1];                                    \
      const int li = (u & 1) ? (ld & 0xffff0000) : (ld << 16);         \
      const int bi = (u & 1) ? (bd & 0xffff0000) : (bd << 16);         \
      const float PL  = __int_as_float(li) + EPSF;                     \
      const float PB  = __int_as_float(bi) + EPSF;                     \
      const float a1p = wf_shr1_f(a1);                /* alpha[2i-1] */\
      const float na0 = (a0 + a1p) * PB;              /* state 2i    */\
      const float na2 = (a2 + a1) * PB;               /* state 2i+2  */\
      const float na1 = fmaf(a1p, mskip, a1 + a0) * PL; /* 2i+1 */     \
      a0 = na0; a1 = na1; a2 = na2;                                    \
    }                                                                  \
  } while (0)

#define RESCALE do {                                                   \
    float m = fmaxf(fmaxf(a0, a1), a2);                                \
    m = dpp_max<0x111>(m); m = dpp_max<0x112>(m);                      \
    m = dpp_max<0x114>(m); m = dpp_max<0x118>(m);                      \
    m = dpp_max<0x142>(m); m = dpp_max<0x143>(m);                      \
    const int mb = __builtin_amdgcn_readlane(__float_as_int(m), 63);   \
    const int k  = 223 - ((mb >> 23) & 0xFF);  /* max -> ~2^96 */      \
    scale += k;                                                        \
    a0 = ldexpf(a0, k); a1 = ldexpf(a1, k); a2 = ldexpf(a2, k);        \
  } while (0)

__global__ void __launch_bounds__(64, 1)
ctc_scan(const int* __restrict__ y_true, const unsigned* __restrict__ Lin,
         const ushort* __restrict__ Bin, float* __restrict__ out) {
  const int b    = blockIdx.x;
  const int lane = threadIdx.x;

  const int lab  = y_true[b * LL + lane];
  const int labp = __builtin_amdgcn_update_dpp(-1, lab, 0x138, 0xF, 0xF, false);
  const float mskip = (lane > 0 && lab != labp) ? 1.0f : 0.0f;

  const char* ql = (const char*)Lin + (size_t)b * 131072 + lane * 16;
  const char* qb = (const char*)Bin + (size_t)b * 2048;   // wave-uniform

  i32x4 Lv[4], Bv[4];
  float a0 = (lane == 0) ? 1.0f : 0.0f;
  float a1 = 0.0f, a2 = 0.0f;
  int scale = 0;

  // prologue: groups 0,1,2 (6 loads outstanding)
  ISSUE(0, 0, 0); ISSUE(1, 1024, 16); ISSUE(2, 2048, 32);

#pragma unroll 1
  for (int it = 0; it < 31; ++it) {
    WAITN(4); ISSUE(3, 3072, 48); STEP8(0);
    ADV;
    WAITN(4); ISSUE(0, 0, 0);     STEP8(1); RESCALE;
    WAITN(4); ISSUE(1, 1024, 16); STEP8(2);
    WAITN(4); ISSUE(2, 2048, 32); STEP8(3); RESCALE;
  }
  // tail: consume 124..127, issue 127
  WAITN(4); ISSUE(3, 3072, 48); STEP8(0);
  WAITN(4);                      STEP8(1); RESCALE;
  WAITN(2);                      STEP8(2);
  WAITN(0);                      STEP8(3); RESCALE;

  if (lane == 63) {
    const float s = a1 + a2;  // alpha[127] + alpha[128] (scaled)
    out[b] = 0.693147180559945f * ((float)scale - log2f(s));
  }
}

// ---------------- Fallback: R9 single-kernel (proven) ----------------
#define GL(dst, ptr, OFF)                                              \
  asm volatile("global_load_dword %0, %1, off offset:" #OFF            \
               : "=&v"(dst) : "v"(ptr))

#define FISSUE(s) do {                                                 \
    GL(Pl[s][0], fql, 0);    GL(Pl[s][1], fql, 384);                   \
    GL(Pl[s][2], fql, 768);  GL(Pl[s][3], fql, 1152);                  \
    GL(Pl[s][4], fql, 1536); GL(Pl[s][5], fql, 1920);                  \
    GL(Pl[s][6], fql, 2304); GL(Pl[s][7], fql, 2688);                  \
    GL(Pb[s][0], fqb, 0);    GL(Pb[s][1], fqb, 384);                   \
    GL(Pb[s][2], fqb, 768);  GL(Pb[s][3], fqb, 1152);                  \
    GL(Pb[s][4], fqb, 1536); GL(Pb[s][5], fqb, 1920);                  \
    GL(Pb[s][6], fqb, 2304); GL(Pb[s][7], fqb, 2688);                  \
    fql += 8 * CC; fqb += 8 * CC;                                      \
  } while (0)

#define FSTEP8(s) do {                                                 \
    _Pragma("unroll")                                                  \
    for (int u = 0; u < 8; ++u) {                                      \
      const float PL  = Pl[s][u] + EPSF;                               \
      const float PB  = Pb[s][u] + EPSF;                               \
      const float a1p = wf_shr1_f(a1);                                 \
      const float na0 = (a0 + a1p) * PB;                               \
      const float na2 = (a2 + a1) * PB;                                \
      const float na1 = fmaf(a1p, mskip, a1 + a0) * PL;                \
      a0 = na0; a1 = na1; a2 = na2;                                    \
    }                                                                  \
  } while (0)

__global__ void __launch_bounds__(64, 1)
ctc_fwd(const int* __restrict__ y_true, const float* __restrict__ y_pred,
        float* __restrict__ out) {
  const int b    = blockIdx.x;
  const int lane = threadIdx.x;
  const int lab  = y_true[b * LL + lane];
  const int labp = __builtin_amdgcn_update_dpp(-1, lab, 0x138, 0xF, 0xF, false);
  const float mskip = (lane > 0 && lab != labp) ? 1.0f : 0.0f;
  const float* __restrict__ p = y_pred + (size_t)b * (TT * CC);
  const float* fql = p + lab;
  const float* fqb = p + (CC - 1);
  float Pl[4][8], Pb[4][8];
  float a0 = (lane == 0) ? 1.0f : 0.0f;
  float a1 = 0.0f, a2 = 0.0f;
  int scale = 0;
  FISSUE(0); FISSUE(1); FISSUE(2);
#pragma unroll 1
  for (int it = 0; it < 31; ++it) {
    WAITN(32); FISSUE(3); FSTEP8(0);
    WAITN(32); FISSUE(0); FSTEP8(1); RESCALE;
    WAITN(32); FISSUE(1); FSTEP8(2);
    WAITN(32); FISSUE(2); FSTEP8(3); RESCALE;
  }
  WAITN(32); FISSUE(3); FSTEP8(0);
  WAITN(32);            FSTEP8(1); RESCALE;
  WAITN(16);            FSTEP8(2);
  WAITN(0);             FSTEP8(3); RESCALE;
  if (lane == 63) {
    const float s = a1 + a2;
    out[b] = 0.693147180559945f * ((float)scale - log2f(s));
  }
}

extern "C" void kernel_launch(void* const* d_in, const int* in_sizes, int n_in,
                              void* d_out, int out_size, void* d_ws, size_t ws_size,
                              hipStream_t stream) {
  (void)in_sizes; (void)n_in; (void)out_size;
  const int*   y_true = (const int*)d_in[0];
  const float* y_pred = (const float*)d_in[1];
  float*       out    = (float*)d_out;

  const size_t l_bytes = (size_t)BB * 128 * 64 * 16;    // 32 MB compact labels
  const size_t b_bytes = (size_t)BB * TT * 2;           // 512 KB blanks
  if (ws_size >= l_bytes + b_bytes) {
    unsigned* L = (unsigned*)d_ws;
    ushort*   Bk = (ushort*)((char*)d_ws + l_bytes);
    ctc_repack<<<BB * 16, 256, 0, stream>>>(y_true, y_pred, L, Bk);
    ctc_scan<<<BB, 64, 0, stream>>>(y_true, L, Bk, out);
  } else {
    ctc_fwd<<<BB, 64, 0, stream>>>(y_true, y_pred, out);  // proven R9 path
  }
}